// Round 5
// baseline (2444.828 us; speedup 1.0000x reference)
//
#include <hip/hip_runtime.h>
#include <stdint.h>

#define T_STEPS 25
#define BB   4096
#define DIN  512
#define DH   1024
#define DOUT 256

struct Keys { uint32_t a[T_STEPS]; uint32_t b[T_STEPS]; };

// Threefry-2x32, exactly as JAX implements it (20 rounds, 5 groups of 4).
__host__ __device__ __forceinline__ void tf2x32(uint32_t k0, uint32_t k1,
                                                uint32_t x0, uint32_t x1,
                                                uint32_t& y0, uint32_t& y1) {
  const uint32_t ks2 = k0 ^ k1 ^ 0x1BD11BDAu;
  x0 += k0; x1 += k1;
#define TFR(r) { x0 += x1; x1 = (x1 << (r)) | (x1 >> (32 - (r))); x1 ^= x0; }
  TFR(13) TFR(15) TFR(26) TFR(6)   x0 += k1;  x1 += ks2 + 1u;
  TFR(17) TFR(29) TFR(16) TFR(24)  x0 += ks2; x1 += k0 + 2u;
  TFR(13) TFR(15) TFR(26) TFR(6)   x0 += k0;  x1 += k1 + 3u;
  TFR(17) TFR(29) TFR(16) TFR(24)  x0 += k1;  x1 += ks2 + 4u;
  TFR(13) TFR(15) TFR(26) TFR(6)   x0 += ks2; x1 += k0 + 5u;
#undef TFR
  y0 = x0; y1 = x1;
}

// Partitionable (modern JAX default) f32 bernoulli keep-bit:
//   bits = y0 ^ y1 of threefry(key, (0, e));  u = (bits>>9)*2^-23;  keep <=> u < 0.8f
__device__ __forceinline__ bool keep_f(uint32_t ka, uint32_t kb, uint32_t e) {
  uint32_t y0, y1;
  tf2x32(ka, kb, 0u, e, y0, y1);
  return (((y0 ^ y1) >> 9) <= 6710886u);
}

// ---- generic transpose: out[k*H + h] = in[h*K + k]
__global__ __launch_bounds__(256) void k_tr(const float* __restrict__ in,
                                            float* __restrict__ out, int H, int K) {
  int e = blockIdx.x * 256 + threadIdx.x;
  if (e < H * K) {
    int h = e / K, k = e - h * K;
    out[(size_t)k * H + h] = in[e];
  }
}

// ---- cur1[b][h] = fma-chain_k( x[b,k]*w1[h,k] ) + b1[h], k ascending (XLA-CPU order)
__global__ __launch_bounds__(256) void k_cur1f(const float* __restrict__ x,
                                               const float* __restrict__ w1t,
                                               const float* __restrict__ b1,
                                               float* __restrict__ cur1) {
  __shared__ float xs[4 * DIN];
  const int bg = blockIdx.x;                 // group of 4 batch rows
  const int h  = blockIdx.y * 256 + threadIdx.x;
  for (int i = threadIdx.x; i < 4 * DIN; i += 256)
    xs[i] = x[(size_t)bg * 4 * DIN + i];
  __syncthreads();
  float a0 = 0.f, a1 = 0.f, a2 = 0.f, a3 = 0.f;
  for (int k = 0; k < DIN; ++k) {
    float w = w1t[(size_t)k * DH + h];
    a0 = __fmaf_rn(xs[k],           w, a0);
    a1 = __fmaf_rn(xs[DIN + k],     w, a1);
    a2 = __fmaf_rn(xs[2 * DIN + k], w, a2);
    a3 = __fmaf_rn(xs[3 * DIN + k], w, a3);
  }
  const float bb = b1[h];
  size_t base = (size_t)bg * 4 * DH + h;
  cur1[base]          = __fadd_rn(a0, bb);
  cur1[base + DH]     = __fadd_rn(a1, bb);
  cur1[base + 2 * DH] = __fadd_rn(a2, bb);
  cur1[base + 3 * DH] = __fadd_rn(a3, bb);
}

// ---- step part A: mem1 update (literal f32, no contraction) + dropout -> spk1d
__global__ __launch_bounds__(256) void k_stepA(const float* __restrict__ cur1,
                                               float* __restrict__ mem1,
                                               float* __restrict__ spk1d,
                                               Keys kk, int t) {
  int e = blockIdx.x * 256 + threadIdx.x;
  float c = cur1[e];
  float m = (t == 0) ? 0.0f : mem1[e];
  float r = (m > 1.0f) ? 1.0f : 0.0f;               // heav(mem1 - 1): sign-exact
  m = __fsub_rn(__fadd_rn(__fmul_rn(0.9f, m), c), r);
  bool spk = m > 1.0f;
  bool kp = keep_f(kk.a[t], kk.b[t], (uint32_t)e);
  spk1d[e] = (spk && kp) ? 1.25f : 0.0f;            // spk1/0.8f == 1.25f exactly
  mem1[e] = m;
}

// ---- step part B: cur2 = fma-chain_k( spk1d[b,k]*w2[o,k] ) + b2; mem2 update; outputs
__global__ __launch_bounds__(256) void k_stepB(const float* __restrict__ spk1d,
                                               const float* __restrict__ w2t,
                                               const float* __restrict__ b2,
                                               float* __restrict__ mem2,
                                               float* __restrict__ out, int t) {
  __shared__ float sd[8 * DH];                      // 8 batch rows of spk1d (32 KB)
  const int bg = blockIdx.x;                        // group of 8 batch rows
  const int o  = threadIdx.x;
  for (int i = threadIdx.x; i < 8 * DH; i += 256)
    sd[i] = spk1d[(size_t)bg * 8 * DH + i];
  __syncthreads();
  float acc[8];
#pragma unroll
  for (int i = 0; i < 8; ++i) acc[i] = 0.0f;
  for (int k = 0; k < DH; ++k) {
    float w = w2t[(size_t)k * DOUT + o];
#pragma unroll
    for (int i = 0; i < 8; ++i)
      acc[i] = __fmaf_rn(sd[i * DH + k], w, acc[i]);
  }
  const float bb = b2[o];
  float* __restrict__ out1 = out + (size_t)T_STEPS * BB * DOUT;
#pragma unroll
  for (int i = 0; i < 8; ++i) {
    int b = bg * 8 + i;
    size_t ip = (size_t)b * DOUT + o;
    float m = (t == 0) ? 0.0f : mem2[ip];
    float c2 = __fadd_rn(acc[i], bb);
    float r = (m > 1.0f) ? 1.0f : 0.0f;
    m = __fsub_rn(__fadd_rn(__fmul_rn(0.9f, m), c2), r);
    bool spk = m > 1.0f;
    size_t p = (size_t)t * (BB * DOUT) + ip;
    out[p]  = spk ? 0.7310585786300049f : 0.5f;     // sigmoid({1,0})
    out1[p] = 1.0f / (1.0f + expf(-m));             // sigmoid(mem2); floor covers ulps
    mem2[ip] = m;
  }
}

extern "C" void kernel_launch(void* const* d_in, const int* in_sizes, int n_in,
                              void* d_out, int out_size, void* d_ws, size_t ws_size,
                              hipStream_t stream) {
  const float* x  = (const float*)d_in[0];
  const float* w1 = (const float*)d_in[1];
  const float* b1 = (const float*)d_in[2];
  const float* w2 = (const float*)d_in[3];
  const float* b2 = (const float*)d_in[4];
  float* out = (float*)d_out;
  char* ws = (char*)d_ws;

  float* w1t   = (float*)(ws);                    //  2 MB  [512][1024]
  float* w2t   = (float*)(ws + 2097152);          //  1 MB  [1024][256]
  float* cur1  = (float*)(ws + 3145728);          // 16 MB
  float* mem1  = (float*)(ws + 19922944);         // 16 MB
  float* spk1d = (float*)(ws + 36700160);         // 16 MB
  float* mem2  = (float*)(ws + 53477376);         //  4 MB  -> 55 MB total

  // partitionable (foldlike) split of key(42): key_t = threefry((0,42),(0,t))
  Keys kk;
  for (int t = 0; t < T_STEPS; ++t) {
    uint32_t y0, y1;
    tf2x32(0u, 42u, 0u, (uint32_t)t, y0, y1);
    kk.a[t] = y0; kk.b[t] = y1;
  }

  k_tr<<<dim3((DH * DIN + 255) / 256), 256, 0, stream>>>(w1, w1t, DH, DIN);
  k_tr<<<dim3((DOUT * DH + 255) / 256), 256, 0, stream>>>(w2, w2t, DOUT, DH);
  k_cur1f<<<dim3(BB / 4, DH / 256), 256, 0, stream>>>(x, w1t, b1, cur1);
  for (int t = 0; t < T_STEPS; ++t) {
    k_stepA<<<dim3(BB * DH / 256), 256, 0, stream>>>(cur1, mem1, spk1d, kk, t);
    k_stepB<<<dim3(BB / 8), 256, 0, stream>>>(spk1d, w2t, b2, mem2, out, t);
  }
}

// Round 6
// 892.578 us; speedup vs baseline: 2.7391x; 2.7391x over previous
//
#include <hip/hip_runtime.h>
#include <stdint.h>

#define T_STEPS 25
#define BB   4096
#define DIN  512
#define DH   1024
#define DOUT 256

struct Keys { uint32_t a[T_STEPS]; uint32_t b[T_STEPS]; };

// Threefry-2x32, exactly as JAX implements it (20 rounds, 5 groups of 4).
__host__ __device__ __forceinline__ void tf2x32(uint32_t k0, uint32_t k1,
                                                uint32_t x0, uint32_t x1,
                                                uint32_t& y0, uint32_t& y1) {
  const uint32_t ks2 = k0 ^ k1 ^ 0x1BD11BDAu;
  x0 += k0; x1 += k1;
#define TFR(r) { x0 += x1; x1 = (x1 << (r)) | (x1 >> (32 - (r))); x1 ^= x0; }
  TFR(13) TFR(15) TFR(26) TFR(6)   x0 += k1;  x1 += ks2 + 1u;
  TFR(17) TFR(29) TFR(16) TFR(24)  x0 += ks2; x1 += k0 + 2u;
  TFR(13) TFR(15) TFR(26) TFR(6)   x0 += k0;  x1 += k1 + 3u;
  TFR(17) TFR(29) TFR(16) TFR(24)  x0 += k1;  x1 += ks2 + 4u;
  TFR(13) TFR(15) TFR(26) TFR(6)   x0 += ks2; x1 += k0 + 5u;
#undef TFR
  y0 = x0; y1 = x1;
}

// Partitionable (modern JAX default) f32 bernoulli keep-bit (verified in R5):
__device__ __forceinline__ bool keep_f(uint32_t ka, uint32_t kb, uint32_t e) {
  uint32_t y0, y1;
  tf2x32(ka, kb, 0u, e, y0, y1);
  return (((y0 ^ y1) >> 9) <= 6710886u);
}

// ---- generic transpose: out[k*H + h] = in[h*K + k]
__global__ __launch_bounds__(256) void k_tr(const float* __restrict__ in,
                                            float* __restrict__ out, int H, int K) {
  int e = blockIdx.x * 256 + threadIdx.x;
  if (e < H * K) {
    int h = e / K, k = e - h * K;
    out[(size_t)k * H + h] = in[e];
  }
}

// ---- cur1[b][h] = fma-chain_k(x[b,k]*w1[h,k]) + b1[h], ascending k, single acc.
// lanes = b (rows); per-lane x from xT (coalesced); w1t row wave-uniform.
__global__ __launch_bounds__(256) void k_cur1s(const float* __restrict__ xT,
                                               const float* __restrict__ w1t,
                                               const float* __restrict__ b1,
                                               float* __restrict__ cur1) {
  const int b  = blockIdx.x * 256 + threadIdx.x;   // one batch row per thread
  const int h0 = blockIdx.y * 32;
  float acc[32];
#pragma unroll
  for (int i = 0; i < 32; ++i) acc[i] = 0.0f;
  for (int k = 0; k < DIN; ++k) {
    float xv = xT[(size_t)k * BB + b];                       // coalesced per-lane
    const float4* wk = (const float4*)(w1t + (size_t)k * DH + h0);  // wave-uniform
#pragma unroll
    for (int q = 0; q < 8; ++q) {
      float4 wv = wk[q];
      acc[q*4+0] = __fmaf_rn(xv, wv.x, acc[q*4+0]);
      acc[q*4+1] = __fmaf_rn(xv, wv.y, acc[q*4+1]);
      acc[q*4+2] = __fmaf_rn(xv, wv.z, acc[q*4+2]);
      acc[q*4+3] = __fmaf_rn(xv, wv.w, acc[q*4+3]);
    }
  }
  float* dst = cur1 + (size_t)b * DH + h0;
#pragma unroll
  for (int q = 0; q < 8; ++q) {
    float4 v;
    v.x = __fadd_rn(acc[q*4+0], b1[h0 + q*4 + 0]);
    v.y = __fadd_rn(acc[q*4+1], b1[h0 + q*4 + 1]);
    v.z = __fadd_rn(acc[q*4+2], b1[h0 + q*4 + 2]);
    v.w = __fadd_rn(acc[q*4+3], b1[h0 + q*4 + 3]);
    *(float4*)(dst + q*4) = v;
  }
}

// ---- all-25-steps mem1 trajectory (strict f32) + dropout -> bit masks along k.
// maskT layout: [t][w=k/32][b] so GEMM lanes (consecutive flat rows) read coalesced.
__global__ __launch_bounds__(256) void k_trajf(const float* __restrict__ cur1,
                                               uint32_t* __restrict__ maskT, Keys kk) {
  const int e = blockIdx.x * 256 + threadIdx.x;    // e = b*1024 + h
  const int lane = threadIdx.x & 63;
  const int b = e >> 10;
  const int w = (e >> 5) & 31;
  const float c = cur1[e];
  float m = 0.0f;
  for (int t = 0; t < T_STEPS; ++t) {
    float r = (m > 1.0f) ? 1.0f : 0.0f;
    m = __fsub_rn(__fadd_rn(__fmul_rn(0.9f, m), c), r);
    bool spk = m > 1.0f;
    bool kp = keep_f(kk.a[t], kk.b[t], (uint32_t)e);
    unsigned long long ball = __ballot(spk && kp);
    if ((lane & 31) == 0)
      maskT[((size_t)t * 32 + w) * BB + b] = (uint32_t)(ball >> (lane & 32));
  }
}

// ---- batched GEMM over all 102400 (t,b) rows: cur2_raw[row][o] =
//      fma-chain_k( sel(row,k) * w2t[k][o] ), sel in {0, 1.25f}; ascending k.
// lanes = rows; weights wave-uniform; masks expanded in-register. No LDS.
__global__ __launch_bounds__(256) void k_gemm2(const uint32_t* __restrict__ maskT,
                                               const float* __restrict__ w2t,
                                               float* __restrict__ cur2) {
  const int row = blockIdx.x * 256 + threadIdx.x;  // flat t*4096+b, same t per block
  const int t = row >> 12, b = row & 4095;
  const int o0 = blockIdx.y * 32;
  const uint32_t* mrow = maskT + (size_t)t * 32 * BB + b;
  float acc[32];
#pragma unroll
  for (int i = 0; i < 32; ++i) acc[i] = 0.0f;
  for (int w = 0; w < 32; ++w) {
    uint32_t word = mrow[(size_t)w * BB];          // coalesced across lanes
    const float* wp = w2t + (size_t)(w * 32) * DOUT + o0;
#pragma unroll 8
    for (int j = 0; j < 32; ++j) {
      float sel = ((word >> j) & 1u) ? 1.25f : 0.0f;
      const float4* wk = (const float4*)(wp + (size_t)j * DOUT);
#pragma unroll
      for (int q = 0; q < 8; ++q) {
        float4 wv = wk[q];
        acc[q*4+0] = __fmaf_rn(sel, wv.x, acc[q*4+0]);
        acc[q*4+1] = __fmaf_rn(sel, wv.y, acc[q*4+1]);
        acc[q*4+2] = __fmaf_rn(sel, wv.z, acc[q*4+2]);
        acc[q*4+3] = __fmaf_rn(sel, wv.w, acc[q*4+3]);
      }
    }
  }
  float* dst = cur2 + (size_t)row * DOUT + o0;
#pragma unroll
  for (int q = 0; q < 8; ++q)
    *(float4*)(dst + q*4) = make_float4(acc[q*4+0], acc[q*4+1], acc[q*4+2], acc[q*4+3]);
}

// ---- mem2 recursion (strict f32) + sigmoids. cur2 aliases out's second half;
// each element is read then overwritten by the same thread in the same t-iter.
__global__ __launch_bounds__(256) void k_out2(const float* __restrict__ b2,
                                              float* __restrict__ out) {
  const int b = blockIdx.x;
  const int o = threadIdx.x;
  float* out1 = out + (size_t)T_STEPS * BB * DOUT;   // == cur2 region
  const float bb = b2[o];
  float m = 0.0f;
  for (int t = 0; t < T_STEPS; ++t) {
    size_t p = ((size_t)t * BB + b) * DOUT + o;
    float c2 = __fadd_rn(out1[p], bb);
    float r = (m > 1.0f) ? 1.0f : 0.0f;
    m = __fsub_rn(__fadd_rn(__fmul_rn(0.9f, m), c2), r);
    out[p]  = (m > 1.0f) ? 0.7310585786300049f : 0.5f;
    out1[p] = 1.0f / (1.0f + expf(-m));
  }
}

extern "C" void kernel_launch(void* const* d_in, const int* in_sizes, int n_in,
                              void* d_out, int out_size, void* d_ws, size_t ws_size,
                              hipStream_t stream) {
  const float* x  = (const float*)d_in[0];
  const float* w1 = (const float*)d_in[1];
  const float* b1 = (const float*)d_in[2];
  const float* w2 = (const float*)d_in[3];
  const float* b2 = (const float*)d_in[4];
  float* out = (float*)d_out;
  char* ws = (char*)d_ws;

  float*    w1t   = (float*)(ws);                   //  2 MB  [512][1024]
  float*    w2t   = (float*)(ws + 2097152);         //  1 MB  [1024][256]
  float*    xT    = (float*)(ws + 3145728);         //  8 MB  [512][4096]
  float*    cur1  = (float*)(ws + 11534336);        // 16 MB  [4096][1024]
  uint32_t* maskT = (uint32_t*)(ws + 28311552);     // 12.8MB [25][32][4096]
                                                    // -> 41.1 MB total
  float*    cur2  = out + (size_t)T_STEPS * BB * DOUT;  // reuse d_out 2nd half

  // partitionable (foldlike) split of key(42): key_t = threefry((0,42),(0,t))
  Keys kk;
  for (int t = 0; t < T_STEPS; ++t) {
    uint32_t y0, y1;
    tf2x32(0u, 42u, 0u, (uint32_t)t, y0, y1);
    kk.a[t] = y0; kk.b[t] = y1;
  }

  k_tr<<<dim3((DH * DIN + 255) / 256), 256, 0, stream>>>(w1, w1t, DH, DIN);
  k_tr<<<dim3((DOUT * DH + 255) / 256), 256, 0, stream>>>(w2, w2t, DOUT, DH);
  k_tr<<<dim3((BB * DIN + 255) / 256), 256, 0, stream>>>(x, xT, BB, DIN);
  k_cur1s<<<dim3(BB / 256, DH / 32), 256, 0, stream>>>(xT, w1t, b1, cur1);
  k_trajf<<<dim3(BB * DH / 256), 256, 0, stream>>>(cur1, maskT, kk);
  k_gemm2<<<dim3(T_STEPS * BB / 256, DOUT / 32), 256, 0, stream>>>(maskT, w2t, cur2);
  k_out2<<<dim3(BB), 256, 0, stream>>>(b2, out);
}